// Round 1
// baseline (1277.347 us; speedup 1.0000x reference)
//
#include <hip/hip_runtime.h>

#define NPTS 500000

// ---------------------------------------------------------------------------
// Transpose (C,H,W) -> (H*W, C) for 3 planes of identical dims (batched on
// blockIdx.y). LDS tile 64 pixels x 64 channels, padded to kill bank conflicts.
// ---------------------------------------------------------------------------
__global__ __launch_bounds__(256) void transpose_chw_hwc(
    const float* __restrict__ p0, const float* __restrict__ p1,
    const float* __restrict__ p2, float* __restrict__ dst, int HW) {
  __shared__ float lds[64][65];
  const float* src = (blockIdx.y == 0) ? p0 : ((blockIdx.y == 1) ? p1 : p2);
  float* out = dst + (size_t)blockIdx.y * (size_t)HW * 64;
  const int pixBase = blockIdx.x * 64;
  const int tid = threadIdx.x;
  const int lane = tid & 63;
  const int quad = tid >> 6;  // 0..3
  // load: lane = pixel (coalesced 256B reads per wave), quad+k = channel
#pragma unroll
  for (int k = 0; k < 16; ++k) {
    const int c = k * 4 + quad;
    lds[c][lane] = src[(size_t)c * HW + pixBase + lane];
  }
  __syncthreads();
  // store: lane = channel (coalesced 256B writes), quad+k = pixel
#pragma unroll
  for (int k = 0; k < 16; ++k) {
    const int pp = k * 4 + quad;
    out[(size_t)(pixBase + pp) * 64 + lane] = lds[lane][pp];
  }
}

// ---------------------------------------------------------------------------
// Keys cubic conv weights, a = -0.75, taps at offsets [-1,0,1,2], t in [0,1)
// ---------------------------------------------------------------------------
__device__ __forceinline__ void cubic_w(float t, float w[4]) {
  const float a = -0.75f;
  const float t1 = t + 1.0f;  // distance of tap -1
  w[0] = ((a * t1 - 5.0f * a) * t1 + 8.0f * a) * t1 - 4.0f * a;
  w[1] = ((a + 2.0f) * t - (a + 3.0f)) * t * t + 1.0f;
  const float u = 1.0f - t;   // distance of tap +1
  w[2] = ((a + 2.0f) * u - (a + 3.0f)) * u * u + 1.0f;
  const float t2 = 2.0f - t;  // distance of tap +2
  w[3] = ((a * t2 - 5.0f * a) * t2 + 8.0f * a) * t2 - 4.0f * a;
}

// ---------------------------------------------------------------------------
// Bicubic sample from transposed (H,W,C) plane; border clamp; align_corners.
// Each thread handles 4 channels (one float4) selected by cg in [0,16).
// ---------------------------------------------------------------------------
__device__ __forceinline__ void sample_acc_hwc(const float* __restrict__ plane,
                                               int W, float gx, float gy,
                                               int cg, float4& acc) {
  const float x = (gx + 1.0f) * 0.5f * (float)(W - 1);
  const float y = (gy + 1.0f) * 0.5f * (float)(W - 1);
  const float x0f = floorf(x), y0f = floorf(y);
  float wx[4], wy[4];
  cubic_w(x - x0f, wx);
  cubic_w(y - y0f, wy);
  const int x0 = (int)x0f, y0 = (int)y0f;
  int ix[4], iy[4];
#pragma unroll
  for (int i = 0; i < 4; ++i) {
    int xi = x0 - 1 + i;
    ix[i] = xi < 0 ? 0 : (xi > W - 1 ? W - 1 : xi);
    int yi = y0 - 1 + i;
    iy[i] = yi < 0 ? 0 : (yi > W - 1 ? W - 1 : yi);
  }
#pragma unroll
  for (int j = 0; j < 4; ++j) {
    const float* rbase = plane + (size_t)iy[j] * W * 64 + cg * 4;
    float4 row = make_float4(0.f, 0.f, 0.f, 0.f);
#pragma unroll
    for (int i = 0; i < 4; ++i) {
      const float4 v = *reinterpret_cast<const float4*>(rbase + ix[i] * 64);
      row.x += wx[i] * v.x;
      row.y += wx[i] * v.y;
      row.z += wx[i] * v.z;
      row.w += wx[i] * v.w;
    }
    acc.x += wy[j] * row.x;
    acc.y += wy[j] * row.y;
    acc.z += wy[j] * row.z;
    acc.w += wy[j] * row.w;
  }
}

__global__ __launch_bounds__(256) void sample_main(
    const float* __restrict__ coords, const float* __restrict__ tp,
    float* __restrict__ out) {
  const int t = blockIdx.x * 256 + threadIdx.x;
  const int pt = t >> 4;
  const int cg = t & 15;  // channel group: 4 channels per thread
  if (pt >= NPTS) return;
  const float cx = (coords[pt * 3 + 0] + 1.0f) * 0.5f;
  const float cy = (coords[pt * 3 + 1] + 1.0f) * 0.5f;
  const float cz = (coords[pt * 3 + 2] + 1.0f) * 0.5f;

  // transposed-plane float offsets: scale0 @0 (plane 4194304 floats),
  // scale1 @12582912 (plane 1048576), scale2 @15728640 (plane 262144)
  const size_t sbase[3] = {0, 12582912, 15728640};
  const int sw[3] = {256, 128, 64};
  float* optr = out + (size_t)pt * 192 + cg * 4;
#pragma unroll
  for (int s = 0; s < 3; ++s) {
    const int W = sw[s];
    const size_t psz = (size_t)W * W * 64;
    const float* bxy = tp + sbase[s];
    float4 acc = make_float4(0.f, 0.f, 0.f, 0.f);
    sample_acc_hwc(bxy, W, cx, cy, cg, acc);            // xy plane (c0,c1)
    sample_acc_hwc(bxy + psz, W, cy, cz, cg, acc);      // yz plane (c1,c2)
    sample_acc_hwc(bxy + 2 * psz, W, cx, cz, cg, acc);  // xz plane (c0,c2)
    *reinterpret_cast<float4*>(optr + s * 64) = acc;
  }
}

// ---------------------------------------------------------------------------
// Fallback: sample straight from (C,H,W) when workspace is too small.
// ---------------------------------------------------------------------------
__device__ __forceinline__ void sample_acc_chw(const float* __restrict__ plane,
                                               int W, float gx, float gy,
                                               int cg, float4& acc) {
  const float x = (gx + 1.0f) * 0.5f * (float)(W - 1);
  const float y = (gy + 1.0f) * 0.5f * (float)(W - 1);
  const float x0f = floorf(x), y0f = floorf(y);
  float wx[4], wy[4];
  cubic_w(x - x0f, wx);
  cubic_w(y - y0f, wy);
  const int x0 = (int)x0f, y0 = (int)y0f;
  int ix[4], iy[4];
#pragma unroll
  for (int i = 0; i < 4; ++i) {
    int xi = x0 - 1 + i;
    ix[i] = xi < 0 ? 0 : (xi > W - 1 ? W - 1 : xi);
    int yi = y0 - 1 + i;
    iy[i] = yi < 0 ? 0 : (yi > W - 1 ? W - 1 : yi);
  }
  const size_t HW = (size_t)W * W;
  float r[4] = {acc.x, acc.y, acc.z, acc.w};
#pragma unroll
  for (int cc = 0; cc < 4; ++cc) {
    const float* pc = plane + (size_t)(cg * 4 + cc) * HW;
    float a = 0.f;
#pragma unroll
    for (int j = 0; j < 4; ++j) {
      const float* rb = pc + (size_t)iy[j] * W;
      float row = 0.f;
#pragma unroll
      for (int i = 0; i < 4; ++i) row += wx[i] * rb[ix[i]];
      a += wy[j] * row;
    }
    r[cc] += a;
  }
  acc = make_float4(r[0], r[1], r[2], r[3]);
}

__global__ __launch_bounds__(256) void sample_fallback(
    const float* __restrict__ coords, const float* __restrict__ px0,
    const float* __restrict__ py0, const float* __restrict__ pz0,
    const float* __restrict__ px1, const float* __restrict__ py1,
    const float* __restrict__ pz1, const float* __restrict__ px2,
    const float* __restrict__ py2, const float* __restrict__ pz2,
    float* __restrict__ out) {
  const int t = blockIdx.x * 256 + threadIdx.x;
  const int pt = t >> 4;
  const int cg = t & 15;
  if (pt >= NPTS) return;
  const float cx = (coords[pt * 3 + 0] + 1.0f) * 0.5f;
  const float cy = (coords[pt * 3 + 1] + 1.0f) * 0.5f;
  const float cz = (coords[pt * 3 + 2] + 1.0f) * 0.5f;
  const float* xs[3] = {px0, px1, px2};
  const float* ys[3] = {py0, py1, py2};
  const float* zs[3] = {pz0, pz1, pz2};
  const int sw[3] = {256, 128, 64};
  float* optr = out + (size_t)pt * 192 + cg * 4;
#pragma unroll
  for (int s = 0; s < 3; ++s) {
    const int W = sw[s];
    float4 acc = make_float4(0.f, 0.f, 0.f, 0.f);
    sample_acc_chw(xs[s], W, cx, cy, cg, acc);
    sample_acc_chw(ys[s], W, cy, cz, cg, acc);
    sample_acc_chw(zs[s], W, cx, cz, cg, acc);
    *reinterpret_cast<float4*>(optr + s * 64) = acc;
  }
}

// ---------------------------------------------------------------------------
extern "C" void kernel_launch(void* const* d_in, const int* in_sizes, int n_in,
                              void* d_out, int out_size, void* d_ws,
                              size_t ws_size, hipStream_t stream) {
  const float* coords = (const float*)d_in[0];
  const float* px0 = (const float*)d_in[1];
  const float* py0 = (const float*)d_in[2];
  const float* pz0 = (const float*)d_in[3];
  const float* px1 = (const float*)d_in[4];
  const float* py1 = (const float*)d_in[5];
  const float* pz1 = (const float*)d_in[6];
  const float* px2 = (const float*)d_in[7];
  const float* py2 = (const float*)d_in[8];
  const float* pz2 = (const float*)d_in[9];
  float* out = (float*)d_out;

  const size_t needed_bytes = 66060288;  // 16,515,072 floats
  const int sample_blocks = (NPTS * 16 + 255) / 256;

  if (ws_size >= needed_bytes) {
    float* tp = (float*)d_ws;
    transpose_chw_hwc<<<dim3(65536 / 64, 3), 256, 0, stream>>>(
        px0, py0, pz0, tp + 0, 65536);
    transpose_chw_hwc<<<dim3(16384 / 64, 3), 256, 0, stream>>>(
        px1, py1, pz1, tp + 12582912, 16384);
    transpose_chw_hwc<<<dim3(4096 / 64, 3), 256, 0, stream>>>(
        px2, py2, pz2, tp + 15728640, 4096);
    sample_main<<<sample_blocks, 256, 0, stream>>>(coords, tp, out);
  } else {
    sample_fallback<<<sample_blocks, 256, 0, stream>>>(
        coords, px0, py0, pz0, px1, py1, pz1, px2, py2, pz2, out);
  }
}